// Round 1
// baseline (450.974 us; speedup 1.0000x reference)
//
#include <hip/hip_runtime.h>

// DiffeomorphicTransform: scaling-and-squaring integration of a velocity field.
//   flow = velocity / 2^7
//   repeat 7x: flow = flow + trilinear_sample(flow, sample_grid + flow_perm)
// Volume: B=1, C=3, D=H=W=128, f32 everywhere.
// Layout: flow/velocity are channel-planar [3][D][H][W]; sample_grid is [D][H][W][3].

#define DD 128
#define HH 128
#define WW 128
#define NVOX (DD * HH * WW)          // 2,097,152
#define NELEM (3 * NVOX)             // 6,291,456

__global__ __launch_bounds__(256) void init_flow_kernel(
    const float* __restrict__ vel, float* __restrict__ flow) {
    int i = blockIdx.x * blockDim.x + threadIdx.x;
    if (i < NELEM) flow[i] = vel[i] * (1.0f / 128.0f);
}

__global__ __launch_bounds__(256) void warp_step_kernel(
    const float* __restrict__ src,     // [3][D][H][W] current flow
    const float* __restrict__ grid,    // [D][H][W][3] sample grid (x,y,z)
    float* __restrict__ dst) {         // [3][D][H][W] next flow
    int idx = blockIdx.x * blockDim.x + threadIdx.x;
    if (idx >= NVOX) return;

    // Per-voxel flow (the displacement we compose with)
    float fx = src[idx];
    float fy = src[NVOX + idx];
    float fz = src[2 * NVOX + idx];

    // Sample grid (x, y, z) in [-1, 1]
    float gx = grid[idx * 3 + 0];
    float gy = grid[idx * 3 + 1];
    float gz = grid[idx * 3 + 2];

    // Unnormalize (align_corners=True): coord = (g + f + 1) * 0.5 * (dim-1)
    float x = (gx + fx + 1.0f) * 0.5f * (float)(WW - 1);
    float y = (gy + fy + 1.0f) * 0.5f * (float)(HH - 1);
    float z = (gz + fz + 1.0f) * 0.5f * (float)(DD - 1);

    float x0f = floorf(x), y0f = floorf(y), z0f = floorf(z);
    float wx = x - x0f, wy = y - y0f, wz = z - z0f;

    // Border padding: clamp indices, weights stay from unclamped floor.
    int x0 = min(max((int)x0f, 0), WW - 1);
    int x1 = min(max((int)x0f + 1, 0), WW - 1);
    int y0 = min(max((int)y0f, 0), HH - 1);
    int y1 = min(max((int)y0f + 1, 0), HH - 1);
    int z0 = min(max((int)z0f, 0), DD - 1);
    int z1 = min(max((int)z0f + 1, 0), DD - 1);

    // Row base offsets for the 4 (z,y) rows
    int o00 = (z0 * HH + y0) * WW;
    int o01 = (z0 * HH + y1) * WW;
    int o10 = (z1 * HH + y0) * WW;
    int o11 = (z1 * HH + y1) * WW;

    float omx = 1.0f - wx, omy = 1.0f - wy, omz = 1.0f - wz;

    #pragma unroll
    for (int c = 0; c < 3; ++c) {
        const float* p = src + c * NVOX;
        float c000 = p[o00 + x0], c001 = p[o00 + x1];
        float c010 = p[o01 + x0], c011 = p[o01 + x1];
        float c100 = p[o10 + x0], c101 = p[o10 + x1];
        float c110 = p[o11 + x0], c111 = p[o11 + x1];
        float top = (c000 * omx + c001 * wx) * omy + (c010 * omx + c011 * wx) * wy;
        float bot = (c100 * omx + c101 * wx) * omy + (c110 * omx + c111 * wx) * wy;
        float val = top * omz + bot * wz;
        float f = (c == 0) ? fx : ((c == 1) ? fy : fz);
        dst[c * NVOX + idx] = f + val;
    }
}

extern "C" void kernel_launch(void* const* d_in, const int* in_sizes, int n_in,
                              void* d_out, int out_size, void* d_ws, size_t ws_size,
                              hipStream_t stream) {
    const float* vel  = (const float*)d_in[0];   // [1,3,128,128,128]
    const float* grid = (const float*)d_in[1];   // [1,128,128,128,3]
    float* out = (float*)d_out;                  // [1,3,128,128,128]
    float* ws  = (float*)d_ws;                   // ping buffer, 3*NVOX floats (24 MiB)

    // flow0 = velocity / 128  -> ws
    init_flow_kernel<<<(NELEM + 255) / 256, 256, 0, stream>>>(vel, ws);

    // 7 warp steps, ping-pong ws <-> out; odd count ends in d_out.
    const float* cur = ws;
    for (int it = 0; it < 7; ++it) {
        float* nxt = (it & 1) ? ws : out;
        warp_step_kernel<<<(NVOX + 255) / 256, 256, 0, stream>>>(cur, grid, nxt);
        cur = nxt;
    }
}

// Round 2
// 277.472 us; speedup vs baseline: 1.6253x; 1.6253x over previous
//
#include <hip/hip_runtime.h>

// DiffeomorphicTransform: scaling-and-squaring integration of a velocity field.
//   flow = velocity / 2^7
//   repeat 7x: flow = flow + trilinear_sample(flow, sample_grid + flow_perm)
// Volume: B=1, C=3, D=H=W=128, f32.
//
// R2: flow kept in AoS float4 layout [D][H][W][4] (pad=0) so each corner gather
// is ONE naturally-aligned dwordx4 covering all 3 channels -> 8 scattered
// wave-loads per voxel instead of 24 (kernel is L1-transaction-bound on
// scattered gathers; see R1 post-mortem). Last step writes planar to d_out.

#define DD 128
#define HH 128
#define WW 128
#define NVOX (DD * HH * WW)          // 2,097,152
#define NELEM (3 * NVOX)             // 6,291,456
#define SCALE 63.5f                  // 0.5*(dim-1), same for x/y/z

// ---------------- AoS fast path ----------------

__global__ __launch_bounds__(256) void init_flow_aos_kernel(
    const float* __restrict__ vel, float4* __restrict__ flow) {
    int i = blockIdx.x * blockDim.x + threadIdx.x;
    if (i >= NVOX) return;
    float4 f;
    f.x = vel[i] * (1.0f / 128.0f);
    f.y = vel[NVOX + i] * (1.0f / 128.0f);
    f.z = vel[2 * NVOX + i] * (1.0f / 128.0f);
    f.w = 0.0f;
    flow[i] = f;
}

template <bool PLANAR_OUT>
__global__ __launch_bounds__(256) void warp_step_aos_kernel(
    const float4* __restrict__ src,    // [NVOX] AoS flow
    const float* __restrict__ grid,    // [D][H][W][3] (x,y,z) in [-1,1]
    float4* __restrict__ dst4,         // AoS out (if !PLANAR_OUT)
    float* __restrict__ dstp) {        // planar out (if PLANAR_OUT)
    int idx = blockIdx.x * blockDim.x + threadIdx.x;
    if (idx >= NVOX) return;

    float4 f = src[idx];

    float gx = grid[3 * idx + 0];
    float gy = grid[3 * idx + 1];
    float gz = grid[3 * idx + 2];

    // Unnormalize (align_corners=True)
    float x = (gx + f.x + 1.0f) * SCALE;
    float y = (gy + f.y + 1.0f) * SCALE;
    float z = (gz + f.z + 1.0f) * SCALE;

    float x0f = floorf(x), y0f = floorf(y), z0f = floorf(z);
    float wx = x - x0f, wy = y - y0f, wz = z - z0f;
    float omx = 1.0f - wx, omy = 1.0f - wy, omz = 1.0f - wz;

    int x0 = min(max((int)x0f, 0), WW - 1);
    int x1 = min(max((int)x0f + 1, 0), WW - 1);
    int y0 = min(max((int)y0f, 0), HH - 1);
    int y1 = min(max((int)y0f + 1, 0), HH - 1);
    int z0 = min(max((int)z0f, 0), DD - 1);
    int z1 = min(max((int)z0f + 1, 0), DD - 1);

    const float4* r00 = src + (z0 * HH + y0) * WW;
    const float4* r01 = src + (z0 * HH + y1) * WW;
    const float4* r10 = src + (z1 * HH + y0) * WW;
    const float4* r11 = src + (z1 * HH + y1) * WW;

    // 8 dwordx4 gathers (all 3 channels per corner)
    float4 c000 = r00[x0], c001 = r00[x1];
    float4 c010 = r01[x0], c011 = r01[x1];
    float4 c100 = r10[x0], c101 = r10[x1];
    float4 c110 = r11[x0], c111 = r11[x1];

    float vx, vy, vzv;
    {
        float t, b, u, v;
        // x-channel
        t = (c000.x * omx + c001.x * wx) * omy + (c010.x * omx + c011.x * wx) * wy;
        b = (c100.x * omx + c101.x * wx) * omy + (c110.x * omx + c111.x * wx) * wy;
        vx = t * omz + b * wz;
        // y-channel
        u = (c000.y * omx + c001.y * wx) * omy + (c010.y * omx + c011.y * wx) * wy;
        v = (c100.y * omx + c101.y * wx) * omy + (c110.y * omx + c111.y * wx) * wy;
        vy = u * omz + v * wz;
        // z-channel
        u = (c000.z * omx + c001.z * wx) * omy + (c010.z * omx + c011.z * wx) * wy;
        v = (c100.z * omx + c101.z * wx) * omy + (c110.z * omx + c111.z * wx) * wy;
        vzv = u * omz + v * wz;
    }

    if (PLANAR_OUT) {
        dstp[idx] = f.x + vx;
        dstp[NVOX + idx] = f.y + vy;
        dstp[2 * NVOX + idx] = f.z + vzv;
    } else {
        float4 o;
        o.x = f.x + vx;
        o.y = f.y + vy;
        o.z = f.z + vzv;
        o.w = 0.0f;
        dst4[idx] = o;
    }
}

// ---------------- planar fallback (R1, used if ws too small) ----------------

__global__ __launch_bounds__(256) void init_flow_kernel(
    const float* __restrict__ vel, float* __restrict__ flow) {
    int i = blockIdx.x * blockDim.x + threadIdx.x;
    if (i < NELEM) flow[i] = vel[i] * (1.0f / 128.0f);
}

__global__ __launch_bounds__(256) void warp_step_kernel(
    const float* __restrict__ src, const float* __restrict__ grid,
    float* __restrict__ dst) {
    int idx = blockIdx.x * blockDim.x + threadIdx.x;
    if (idx >= NVOX) return;

    float fx = src[idx];
    float fy = src[NVOX + idx];
    float fz = src[2 * NVOX + idx];
    float gx = grid[idx * 3 + 0];
    float gy = grid[idx * 3 + 1];
    float gz = grid[idx * 3 + 2];

    float x = (gx + fx + 1.0f) * SCALE;
    float y = (gy + fy + 1.0f) * SCALE;
    float z = (gz + fz + 1.0f) * SCALE;

    float x0f = floorf(x), y0f = floorf(y), z0f = floorf(z);
    float wx = x - x0f, wy = y - y0f, wz = z - z0f;

    int x0 = min(max((int)x0f, 0), WW - 1);
    int x1 = min(max((int)x0f + 1, 0), WW - 1);
    int y0 = min(max((int)y0f, 0), HH - 1);
    int y1 = min(max((int)y0f + 1, 0), HH - 1);
    int z0 = min(max((int)z0f, 0), DD - 1);
    int z1 = min(max((int)z0f + 1, 0), DD - 1);

    int o00 = (z0 * HH + y0) * WW;
    int o01 = (z0 * HH + y1) * WW;
    int o10 = (z1 * HH + y0) * WW;
    int o11 = (z1 * HH + y1) * WW;

    float omx = 1.0f - wx, omy = 1.0f - wy, omz = 1.0f - wz;

    #pragma unroll
    for (int c = 0; c < 3; ++c) {
        const float* p = src + c * NVOX;
        float c000 = p[o00 + x0], c001 = p[o00 + x1];
        float c010 = p[o01 + x0], c011 = p[o01 + x1];
        float c100 = p[o10 + x0], c101 = p[o10 + x1];
        float c110 = p[o11 + x0], c111 = p[o11 + x1];
        float top = (c000 * omx + c001 * wx) * omy + (c010 * omx + c011 * wx) * wy;
        float bot = (c100 * omx + c101 * wx) * omy + (c110 * omx + c111 * wx) * wy;
        float val = top * omz + bot * wz;
        float fcur = (c == 0) ? fx : ((c == 1) ? fy : fz);
        dst[c * NVOX + idx] = fcur + val;
    }
}

// ---------------- launch ----------------

extern "C" void kernel_launch(void* const* d_in, const int* in_sizes, int n_in,
                              void* d_out, int out_size, void* d_ws, size_t ws_size,
                              hipStream_t stream) {
    const float* vel  = (const float*)d_in[0];   // [1,3,128,128,128]
    const float* grid = (const float*)d_in[1];   // [1,128,128,128,3]
    float* out = (float*)d_out;

    const size_t aos_bytes = (size_t)NVOX * 16;  // 32 MiB per buffer

    if (ws_size >= 2 * aos_bytes) {
        float4* A = (float4*)d_ws;
        float4* B = A + NVOX;

        init_flow_aos_kernel<<<(NVOX + 255) / 256, 256, 0, stream>>>(vel, A);

        const float4* cur = A;
        for (int it = 0; it < 6; ++it) {
            float4* nxt = (it & 1) ? A : B;
            warp_step_aos_kernel<false><<<(NVOX + 255) / 256, 256, 0, stream>>>(
                cur, grid, nxt, nullptr);
            cur = nxt;
        }
        // Final step writes planar f32 directly to d_out.
        warp_step_aos_kernel<true><<<(NVOX + 255) / 256, 256, 0, stream>>>(
            cur, grid, nullptr, out);
    } else {
        // Fallback: planar ping-pong (R1 path), needs only 24 MiB of ws.
        float* ws = (float*)d_ws;
        init_flow_kernel<<<(NELEM + 255) / 256, 256, 0, stream>>>(vel, ws);
        const float* cur = ws;
        for (int it = 0; it < 7; ++it) {
            float* nxt = (it & 1) ? ws : out;
            warp_step_kernel<<<(NVOX + 255) / 256, 256, 0, stream>>>(cur, grid, nxt);
            cur = nxt;
        }
    }
}